// Round 1
// baseline (99.174 us; speedup 1.0000x reference)
//
#include <hip/hip_runtime.h>
#include <stdint.h>

// RBF kernel attention, MI355X.
// N=4, L=S=2048, H=8, E=D=64.
// out[n,l,h,d] = Z[n,h,l] * sum_s phi[n,h,l,s] * V[n,s,h,d]
// phi = exp(-0.0625*max(qsq+ksq-2*qk,0)) * mask[n,s],  Z = 1/(rowsum+1e-6)
// Q,K indexed as [n][h][row][64] (torch .view reshape of contiguous buffer).
//
// ws layout (needs ~24.75 MB):
//   [0,8MB)    Q bf16   [n][h][l][64]
//   [8,16MB)   K bf16   [n][h][s][64]
//   [16,24MB)  V^T bf16 [n][h][d][s]
//   [24MB,+256KB)  qsq f32 [n][h][l]
//   [+256KB,+512KB) ksq f32 [n][h][s]

#define N_ 4
#define L_ 2048
#define H_ 8
#define S_ 2048

typedef unsigned short ushort_t;
typedef unsigned int uint_t;
typedef __bf16 b8 __attribute__((ext_vector_type(8)));
typedef float f4 __attribute__((ext_vector_type(4)));
typedef const __attribute__((address_space(1))) uint32_t* gas_ptr;
typedef __attribute__((address_space(3))) uint32_t* las_ptr;

static __device__ __forceinline__ ushort_t f2bf(float x) {
  uint32_t u = __float_as_uint(x);
  u += 0x7fffu + ((u >> 16) & 1u);   // round-to-nearest-even
  return (ushort_t)(u >> 16);
}

// fp32 -> bf16 convert + per-64-elem-row sum of squares. 4 threads/row.
__global__ __launch_bounds__(256) void k_cvt(const float* __restrict__ src,
                                             ushort_t* __restrict__ dst,
                                             float* __restrict__ sq) {
  int t = blockIdx.x * 256 + threadIdx.x;
  int row = t >> 2, part = t & 3;
  const float4* p = reinterpret_cast<const float4*>(src + (size_t)row * 64 + part * 16);
  uint_t o[8];
  float s = 0.f;
#pragma unroll
  for (int i = 0; i < 4; ++i) {
    float4 v = p[i];
    s += v.x * v.x + v.y * v.y + v.z * v.z + v.w * v.w;
    o[2 * i]     = (uint_t)f2bf(v.x) | ((uint_t)f2bf(v.y) << 16);
    o[2 * i + 1] = (uint_t)f2bf(v.z) | ((uint_t)f2bf(v.w) << 16);
  }
  uint4* dp = reinterpret_cast<uint4*>(dst + (size_t)row * 64 + part * 16);
  dp[0] = make_uint4(o[0], o[1], o[2], o[3]);
  dp[1] = make_uint4(o[4], o[5], o[6], o[7]);
  s += __shfl_xor(s, 1);
  s += __shfl_xor(s, 2);
  if (part == 0) sq[row] = s;
}

// V [n][s][h][64] fp32 -> V^T bf16 [n][h][d][s], 64x64 tile per block via LDS.
__global__ __launch_bounds__(256) void k_vt(const float* __restrict__ v,
                                            ushort_t* __restrict__ vt) {
  __shared__ __align__(16) ushort_t tile[64][68];
  const int n = blockIdx.z, h = blockIdx.y, sc = blockIdx.x;
  const int t = threadIdx.x;
  const int sl = t >> 4;           // 0..15
  const int dp = (t & 15) * 4;     // d start
#pragma unroll
  for (int i = 0; i < 4; ++i) {
    int s = sc * 64 + i * 16 + sl;
    float4 val = *reinterpret_cast<const float4*>(
        v + (((size_t)n * S_ + s) * H_ + h) * 64 + dp);
    tile[dp + 0][i * 16 + sl] = f2bf(val.x);
    tile[dp + 1][i * 16 + sl] = f2bf(val.y);
    tile[dp + 2][i * 16 + sl] = f2bf(val.z);
    tile[dp + 3][i * 16 + sl] = f2bf(val.w);
  }
  __syncthreads();
  const int d = t >> 2, sp = (t & 3) * 16;
  uint_t o[8];
#pragma unroll
  for (int i = 0; i < 8; ++i)
    o[i] = (uint_t)tile[d][sp + 2 * i] | ((uint_t)tile[d][sp + 2 * i + 1] << 16);
  size_t base = ((size_t)(n * H_ + h) * 64 + d) * S_ + sc * 64 + sp;
  uint4* w = reinterpret_cast<uint4*>(vt + base);
  w[0] = make_uint4(o[0], o[1], o[2], o[3]);
  w[1] = make_uint4(o[4], o[5], o[6], o[7]);
}

// Main fused kernel. Block = 4 waves; wave owns 16 q-rows; chunk = 64 keys.
__global__ __launch_bounds__(256) void k_attn(
    const ushort_t* __restrict__ qb, const ushort_t* __restrict__ kb,
    const ushort_t* __restrict__ vt, const float* __restrict__ qsq,
    const float* __restrict__ ksq, const float* __restrict__ mask,
    float* __restrict__ out) {
  // K tile [s][e], V^T tile [d][s]: linear rows of 128B, global source
  // pre-swizzled (16B slot ^= row&7) so frag ds_read_b128 is ~conflict-free.
  __shared__ __align__(16) ushort_t kt[64 * 64];
  __shared__ __align__(16) ushort_t vtt[64 * 64];
  __shared__ __align__(16) ushort_t pt[4][16 * 72];  // per-wave phi, pad stride 72

  const int lane = threadIdx.x & 63;
  const int w = threadIdx.x >> 6;
  const int qt = blockIdx.x;
  const int h = blockIdx.y;
  const int n = blockIdx.z;
  const int nh = n * H_ + h;
  const int c = lane & 15;   // MFMA col / A-row lane id
  const int g = lane >> 4;   // MFMA k-group
  const int qrow = qt * 64 + w * 16;

  // Q A-fragments (row = c, e = estep*32 + g*8 + b), straight from global bf16
  const ushort_t* qbase = qb + ((size_t)nh * L_ + qrow) * 64;
  b8 qf0 = *reinterpret_cast<const b8*>(qbase + c * 64 + g * 8);
  b8 qf1 = *reinterpret_cast<const b8*>(qbase + c * 64 + 32 + g * 8);

  float qs[4];
#pragma unroll
  for (int r = 0; r < 4; ++r) qs[r] = qsq[(size_t)nh * L_ + qrow + 4 * g + r];

  const float* kseb = ksq + (size_t)nh * S_;
  const float* mskb = mask + (size_t)n * S_;
  const ushort_t* kbh = kb + (size_t)nh * S_ * 64;
  const ushort_t* vth = vt + (size_t)nh * 64 * S_;

  f4 acc[4];
#pragma unroll
  for (int i = 0; i < 4; ++i) acc[i] = (f4){0.f, 0.f, 0.f, 0.f};
  float rs[4] = {0.f, 0.f, 0.f, 0.f};

  const int lrow = lane >> 3;               // staging: row within 8-row group
  const int lc16 = (lane & 7) ^ lrow;       // swizzled global 16B slot
  ushort_t* myp = pt[w];

  for (int ch = 0; ch < 32; ++ch) {
    __syncthreads();  // previous chunk fully consumed
#pragma unroll
    for (int t2 = 0; t2 < 2; ++t2) {
      const int rr = w * 16 + t2 * 8;  // base row of this 8-row / 1KB piece
      const ushort_t* gk = kbh + ((size_t)ch * 64 + rr + lrow) * 64 + lc16 * 8;
      __builtin_amdgcn_global_load_lds((gas_ptr)gk, (las_ptr)(kt + rr * 64), 16, 0, 0);
      const ushort_t* gv = vth + (size_t)(rr + lrow) * S_ + ch * 64 + lc16 * 8;
      __builtin_amdgcn_global_load_lds((gas_ptr)gv, (las_ptr)(vtt + rr * 64), 16, 0, 0);
    }
    __syncthreads();  // staged (compiler drains vmcnt before s_barrier)

    // QK^T + exp + mask + rowsum + phi->LDS (A-layout source)
#pragma unroll
    for (int ss = 0; ss < 4; ++ss) {
      const int sl = ss * 16 + c;  // local key column
      f4 sa = {0.f, 0.f, 0.f, 0.f};
      b8 bk0 = *reinterpret_cast<const b8*>(kt + sl * 64 + ((g ^ (sl & 7)) * 8));
      sa = __builtin_amdgcn_mfma_f32_16x16x32_bf16(qf0, bk0, sa, 0, 0, 0);
      b8 bk1 = *reinterpret_cast<const b8*>(kt + sl * 64 + (((4 + g) ^ (sl & 7)) * 8));
      sa = __builtin_amdgcn_mfma_f32_16x16x32_bf16(qf1, bk1, sa, 0, 0, 0);
      const float kv = kseb[ch * 64 + sl];
      const float mv = mskb[ch * 64 + sl];
#pragma unroll
      for (int r = 0; r < 4; ++r) {
        float dist = fmaxf(qs[r] + kv - 2.f * sa[r], 0.f);
        float ph = __expf(-0.0625f * dist) * mv;
        rs[r] += ph;
        myp[(4 * g + r) * 72 + sl] = f2bf(ph);
      }
    }

    // PV: acc[ds] += phi(16l x 32s) * V^T-as-B(32s x 16d)
#pragma unroll
    for (int sst = 0; sst < 2; ++sst) {
      b8 pa = *reinterpret_cast<const b8*>(myp + c * 72 + sst * 32 + g * 8);
      const int cq = 4 * sst + g;
#pragma unroll
      for (int ds2 = 0; ds2 < 4; ++ds2) {
        const int dr = ds2 * 16 + c;
        b8 bv = *reinterpret_cast<const b8*>(vtt + dr * 64 + ((cq ^ (dr & 7)) * 8));
        acc[ds2] = __builtin_amdgcn_mfma_f32_16x16x32_bf16(pa, bv, acc[ds2], 0, 0, 0);
      }
    }
  }

  // rowsum reduce across the 16 lanes of each k-group (cols) -> Z
#pragma unroll
  for (int m = 1; m < 16; m <<= 1) {
#pragma unroll
    for (int r = 0; r < 4; ++r) rs[r] += __shfl_xor(rs[r], m);
  }
  float z[4];
#pragma unroll
  for (int r = 0; r < 4; ++r) z[r] = 1.f / (rs[r] + 1e-6f);

  // out[n][qrow+4g+r][h][ds*16+c]
  float* ob = out + (((size_t)n * L_ + qrow + 4 * g) * H_ + h) * 64;
#pragma unroll
  for (int ds2 = 0; ds2 < 4; ++ds2) {
#pragma unroll
    for (int r = 0; r < 4; ++r) {
      ob[(size_t)r * (H_ * 64) + ds2 * 16 + c] = acc[ds2][r] * z[r];
    }
  }
}

extern "C" void kernel_launch(void* const* d_in, const int* in_sizes, int n_in,
                              void* d_out, int out_size, void* d_ws, size_t ws_size,
                              hipStream_t stream) {
  const float* q = (const float*)d_in[0];
  const float* k = (const float*)d_in[1];
  const float* v = (const float*)d_in[2];
  const float* mask = (const float*)d_in[3];
  float* out = (float*)d_out;

  char* ws = (char*)d_ws;
  ushort_t* qb = (ushort_t*)ws;
  ushort_t* kb = (ushort_t*)(ws + ((size_t)8 << 20));
  ushort_t* vt = (ushort_t*)(ws + ((size_t)16 << 20));
  float* qsq = (float*)(ws + ((size_t)24 << 20));
  float* ksq = (float*)(ws + ((size_t)24 << 20) + ((size_t)1 << 18));

  // 65536 rows each, 4 threads/row -> 1024 blocks of 256
  k_cvt<<<dim3(1024), dim3(256), 0, stream>>>(q, qb, qsq);
  k_cvt<<<dim3(1024), dim3(256), 0, stream>>>(k, kb, ksq);
  k_vt<<<dim3(S_ / 64, H_, N_), dim3(256), 0, stream>>>(v, vt);
  k_attn<<<dim3(L_ / 64, H_, N_), dim3(256), 0, stream>>>(qb, kb, vt, qsq, ksq,
                                                          mask, out);
}

// Round 2
// 92.719 us; speedup vs baseline: 1.0696x; 1.0696x over previous
//
#include <hip/hip_runtime.h>
#include <stdint.h>

// RBF kernel attention, MI355X. N=4, L=S=2048, H=8, E=D=64.
// Factorized: phi = A_l * p,  p = exp2(c1*qk + lb_s),
//   lb_s = -c2*k^2 + log2(mask_s),  A_l = exp2(-c2*q^2)  (cancels in Z),
//   out = (sum p*V) / (sum p + 1e-6*exp2(+c2*q^2)),  c1=t*log2e, c2=(t/2)*log2e.
//
// ws layout:
//   [0,8MB)    Q bf16   [n][h][l][64]
//   [8,16MB)   K bf16   [n][h][s][64]
//   [16,24MB)  V^T bf16 [n][h][d][sigma(s)]   (column-permuted, see sigma)
//   [24MB,+256KB)   epsq f32 [n][h][l] = 1e-6*exp2(+c2*q^2)
//   [+256KB,+512KB) lb   f32 [n][h][s]

#define N_ 4
#define L_ 2048
#define H_ 8
#define S_ 2048

#define C1 0.18033688f   // 0.125 * log2(e)
#define C2 0.09016844f   // 0.0625 * log2(e)

typedef unsigned short ushort_t;
typedef unsigned int uint_t;
typedef __bf16 b8 __attribute__((ext_vector_type(8)));
typedef float f4 __attribute__((ext_vector_type(4)));
typedef const __attribute__((address_space(1))) uint32_t* gas_ptr;
typedef __attribute__((address_space(3))) uint32_t* las_ptr;

static __device__ __forceinline__ ushort_t f2bf(float x) {
  uint32_t u = __float_as_uint(x);
  u += 0x7fffu + ((u >> 16) & 1u);   // round-to-nearest-even
  return (ushort_t)(u >> 16);
}

// fp32 -> bf16 convert + per-64-row sum of squares -> aux transform.
// MODE 0 (Q): aux[row] = 1e-6 * exp2(+C2*sumsq)
// MODE 1 (K): aux[row] = -C2*sumsq + log2(mask[n][s])
template <int MODE>
__global__ __launch_bounds__(256) void k_cvt(const float* __restrict__ src,
                                             ushort_t* __restrict__ dst,
                                             float* __restrict__ aux,
                                             const float* __restrict__ mask) {
  int t = blockIdx.x * 256 + threadIdx.x;
  int row = t >> 2, part = t & 3;
  const float4* p = reinterpret_cast<const float4*>(src + (size_t)row * 64 + part * 16);
  uint_t o[8];
  float s = 0.f;
#pragma unroll
  for (int i = 0; i < 4; ++i) {
    float4 v = p[i];
    s += v.x * v.x + v.y * v.y + v.z * v.z + v.w * v.w;
    o[2 * i]     = (uint_t)f2bf(v.x) | ((uint_t)f2bf(v.y) << 16);
    o[2 * i + 1] = (uint_t)f2bf(v.z) | ((uint_t)f2bf(v.w) << 16);
  }
  uint4* dp = reinterpret_cast<uint4*>(dst + (size_t)row * 64 + part * 16);
  dp[0] = make_uint4(o[0], o[1], o[2], o[3]);
  dp[1] = make_uint4(o[4], o[5], o[6], o[7]);
  s += __shfl_xor(s, 1);
  s += __shfl_xor(s, 2);
  if (part == 0) {
    if (MODE == 0) {
      aux[row] = 1e-6f * exp2f(C2 * s);
    } else {
      int n = row >> 14;          // / (H*S)
      int sidx = row & (S_ - 1);  // % S
      float m = mask[n * S_ + sidx];
      aux[row] = -C2 * s + __log2f(m);
    }
  }
}

// V [n][s][h][64] fp32 -> V^T bf16 [n][h][d][sigma(s)], 64x64 tile via LDS.
// sigma (within each 64-col chunk): stored position p holds source
//   s = (p&32) + ((p>>2)&1)*16 + ((p>>3)&3)*4 + (p&3)
// so that PV B-fragment (keys 32sst+4g+16(b>>2)+(b&3), b=0..7) is one b128.
__global__ __launch_bounds__(256) void k_vt(const float* __restrict__ v,
                                            ushort_t* __restrict__ vt) {
  __shared__ __align__(16) ushort_t tile[64][68];
  const int n = blockIdx.z, h = blockIdx.y, sc = blockIdx.x;
  const int t = threadIdx.x;
  const int sl = t >> 4;
  const int dp = (t & 15) * 4;
#pragma unroll
  for (int i = 0; i < 4; ++i) {
    int s = sc * 64 + i * 16 + sl;
    float4 val = *reinterpret_cast<const float4*>(
        v + (((size_t)n * S_ + s) * H_ + h) * 64 + dp);
    tile[dp + 0][i * 16 + sl] = f2bf(val.x);
    tile[dp + 1][i * 16 + sl] = f2bf(val.y);
    tile[dp + 2][i * 16 + sl] = f2bf(val.z);
    tile[dp + 3][i * 16 + sl] = f2bf(val.w);
  }
  __syncthreads();
  const int d = t >> 2, sp = (t & 3) * 16;
  uint_t o[8];
#pragma unroll
  for (int i = 0; i < 8; ++i) {
    const int p0 = sp + 2 * i, p1 = p0 + 1;
    const int s0 = (p0 & 32) + (((p0 >> 2) & 1) << 4) + (((p0 >> 3) & 3) << 2) + (p0 & 3);
    const int s1 = (p1 & 32) + (((p1 >> 2) & 1) << 4) + (((p1 >> 3) & 3) << 2) + (p1 & 3);
    o[i] = (uint_t)tile[d][s0] | ((uint_t)tile[d][s1] << 16);
  }
  size_t base = ((size_t)(n * H_ + h) * 64 + d) * S_ + sc * 64 + sp;
  uint4* w = reinterpret_cast<uint4*>(vt + base);
  w[0] = make_uint4(o[0], o[1], o[2], o[3]);
  w[1] = make_uint4(o[4], o[5], o[6], o[7]);
}

// Main fused kernel. 4 waves/block; wave owns 16 q-rows; chunk = 64 keys.
// Swapped QK^T: sa = mfma(K_frag, Q_frag) -> D[key][qrow]; lane (c,g) holds
// p for qrow=c, keys ss*16+4g+r  -> cvt_pk pairs ARE the PV A-frag (k-map
// permuted; V^T storage pre-permuted by sigma to match).
__global__ __launch_bounds__(256) void k_attn(
    const ushort_t* __restrict__ qb, const ushort_t* __restrict__ kb,
    const ushort_t* __restrict__ vt, const float* __restrict__ epsq,
    const float* __restrict__ lb, float* __restrict__ out) {
  __shared__ __align__(16) ushort_t kt[64 * 64];
  __shared__ __align__(16) ushort_t vtt[64 * 64];
  __shared__ float zb[4][16];

  const int lane = threadIdx.x & 63;
  const int w = threadIdx.x >> 6;
  const int qt = blockIdx.x;
  const int h = blockIdx.y;
  const int n = blockIdx.z;
  const int nh = n * H_ + h;
  const int c = lane & 15;
  const int g = lane >> 4;
  const int qrow = qt * 64 + w * 16;

  // Q as MFMA B-operand: lane (c,g) holds Q[qrow0+c][e = ek*32 + g*8 + b]
  const ushort_t* qbase = qb + ((size_t)nh * L_ + qrow) * 64;
  b8 qf0 = *reinterpret_cast<const b8*>(qbase + c * 64 + g * 8);
  b8 qf1 = *reinterpret_cast<const b8*>(qbase + c * 64 + 32 + g * 8);

  const float* lbh = lb + (size_t)nh * S_;
  const ushort_t* kbh = kb + (size_t)nh * S_ * 64;
  const ushort_t* vth = vt + (size_t)nh * 64 * S_;

  f4 acc[4];
#pragma unroll
  for (int i = 0; i < 4; ++i) acc[i] = (f4){0.f, 0.f, 0.f, 0.f};
  float rs = 0.f;

  const int lrow = lane >> 3;          // staging row within 8-row group
  const int lc16 = (lane & 7) ^ lrow;  // swizzled global 16B slot

  for (int ch = 0; ch < 32; ++ch) {
    __syncthreads();  // previous chunk fully consumed
#pragma unroll
    for (int t2 = 0; t2 < 2; ++t2) {
      const int rr = w * 16 + t2 * 8;
      const ushort_t* gk = kbh + ((size_t)ch * 64 + rr + lrow) * 64 + lc16 * 8;
      __builtin_amdgcn_global_load_lds((gas_ptr)gk, (las_ptr)(kt + rr * 64), 16, 0, 0);
      const ushort_t* gv = vth + (size_t)(rr + lrow) * S_ + ch * 64 + lc16 * 8;
      __builtin_amdgcn_global_load_lds((gas_ptr)gv, (las_ptr)(vtt + rr * 64), 16, 0, 0);
    }
    __syncthreads();  // staged

    // QK^T (swapped) + p = exp2(c1*qk + lb) + rowsum + pack
    uint_t pw[8];
#pragma unroll
    for (int ss = 0; ss < 4; ++ss) {
      const int sl = ss * 16 + c;  // key row in K tile
      f4 sa = {0.f, 0.f, 0.f, 0.f};
      b8 ak0 = *reinterpret_cast<const b8*>(kt + sl * 64 + ((g ^ (sl & 7)) * 8));
      sa = __builtin_amdgcn_mfma_f32_16x16x32_bf16(ak0, qf0, sa, 0, 0, 0);
      b8 ak1 = *reinterpret_cast<const b8*>(kt + sl * 64 + (((4 + g) ^ (sl & 7)) * 8));
      sa = __builtin_amdgcn_mfma_f32_16x16x32_bf16(ak1, qf1, sa, 0, 0, 0);
      const float4 l4 = *reinterpret_cast<const float4*>(lbh + ch * 64 + ss * 16 + 4 * g);
      float p0 = exp2f(fmaf(C1, sa[0], l4.x));
      float p1 = exp2f(fmaf(C1, sa[1], l4.y));
      float p2 = exp2f(fmaf(C1, sa[2], l4.z));
      float p3 = exp2f(fmaf(C1, sa[3], l4.w));
      rs += (p0 + p1) + (p2 + p3);
      asm("v_cvt_pk_bf16_f32 %0, %1, %2" : "=v"(pw[2 * ss]) : "v"(p0), "v"(p1));
      asm("v_cvt_pk_bf16_f32 %0, %1, %2" : "=v"(pw[2 * ss + 1]) : "v"(p2), "v"(p3));
    }

    // PV: acc[dblk] += P(16l x 32s, permuted k-map) * V'(32s x 16d)
#pragma unroll
    for (int sst = 0; sst < 2; ++sst) {
      union { uint_t u[4]; b8 v; } pa;
      pa.u[0] = pw[4 * sst + 0];
      pa.u[1] = pw[4 * sst + 1];
      pa.u[2] = pw[4 * sst + 2];
      pa.u[3] = pw[4 * sst + 3];
#pragma unroll
      for (int dblk = 0; dblk < 4; ++dblk) {
        const int dr = dblk * 16 + c;
        b8 bv = *reinterpret_cast<const b8*>(
            vtt + dr * 64 + (((4 * sst + g) ^ (dr & 7)) * 8));
        acc[dblk] = __builtin_amdgcn_mfma_f32_16x16x32_bf16(pa.v, bv, acc[dblk], 0, 0, 0);
      }
    }
  }

  // Z per q-row: lane (c,g) has partial rowsum for qrow c; reduce over g.
  rs += __shfl_xor(rs, 16);
  rs += __shfl_xor(rs, 32);
  if (g == 0) zb[w][c] = 1.0f / (rs + epsq[(size_t)nh * L_ + qrow + c]);
  __syncthreads();
  const float4 z4 = *reinterpret_cast<const float4*>(&zb[w][4 * g]);
  const float zz[4] = {z4.x, z4.y, z4.z, z4.w};

  // out[n][qrow+4g+r][h][dblk*16+c]
  float* ob = out + (((size_t)n * L_ + qrow + 4 * g) * H_ + h) * 64;
#pragma unroll
  for (int dblk = 0; dblk < 4; ++dblk) {
#pragma unroll
    for (int r = 0; r < 4; ++r) {
      ob[(size_t)r * (H_ * 64) + dblk * 16 + c] = acc[dblk][r] * zz[r];
    }
  }
}

extern "C" void kernel_launch(void* const* d_in, const int* in_sizes, int n_in,
                              void* d_out, int out_size, void* d_ws, size_t ws_size,
                              hipStream_t stream) {
  const float* q = (const float*)d_in[0];
  const float* k = (const float*)d_in[1];
  const float* v = (const float*)d_in[2];
  const float* mask = (const float*)d_in[3];
  float* out = (float*)d_out;

  char* ws = (char*)d_ws;
  ushort_t* qb = (ushort_t*)ws;
  ushort_t* kb = (ushort_t*)(ws + ((size_t)8 << 20));
  ushort_t* vt = (ushort_t*)(ws + ((size_t)16 << 20));
  float* epsq = (float*)(ws + ((size_t)24 << 20));
  float* lbuf = (float*)(ws + ((size_t)24 << 20) + ((size_t)1 << 18));

  k_cvt<0><<<dim3(1024), dim3(256), 0, stream>>>(q, qb, epsq, nullptr);
  k_cvt<1><<<dim3(1024), dim3(256), 0, stream>>>(k, kb, lbuf, mask);
  k_vt<<<dim3(S_ / 64, H_, N_), dim3(256), 0, stream>>>(v, vt);
  k_attn<<<dim3(L_ / 64, H_, N_), dim3(256), 0, stream>>>(qb, kb, vt, epsq,
                                                          lbuf, out);
}

// Round 3
// 87.361 us; speedup vs baseline: 1.1352x; 1.0613x over previous
//
#include <hip/hip_runtime.h>
#include <stdint.h>

// RBF kernel attention, MI355X. N=4, L=S=2048, H=8, E=D=64.
// phi = exp(-1/16*(q^2+k^2-2qk)) * mask; out = (phi V) / (rowsum(phi)+eps)
// Factorized: p = exp2(C1*(qk + lb')), lb' = -k^2/2 + 8*ln(mask)  (q^2 cancels;
// epilogue eps' = 1e-6*exp2(C2*q^2)).  C1 = log2(e)/8.
// Round-3 structure: 32x32x16 MFMA, 32 q-rows/wave, lb folded into QK via an
// extra MFMA slice, double-buffered LDS staging, 1 barrier/chunk.
//
// ws layout:
//   [0,8MB)    Q bf16   [n][h][l][64]
//   [8,16MB)   K bf16   [n][h][s][64]
//   [16,24MB)  V^T bf16 [n][h][d][sigma(s)]   (bit2<->bit3 swap in low nibble)
//   [24MB,+256KB)   epsq f32 [n][h][l]
//   [+256KB,+512KB) lbp  u32 [n][h][s] = packed (bf16 hi | bf16 lo << 16) of lb'

#define N_ 4
#define L_ 2048
#define H_ 8
#define S_ 2048

#define C1 0.18033688f   // log2(e)/8
#define C2 0.09016844f   // log2(e)/16

typedef unsigned short ushort_t;
typedef unsigned int uint_t;
typedef __bf16 b8 __attribute__((ext_vector_type(8)));
typedef float f4 __attribute__((ext_vector_type(4)));
typedef float f16v __attribute__((ext_vector_type(16)));
typedef const __attribute__((address_space(1))) uint32_t* gas_ptr;
typedef __attribute__((address_space(3))) uint32_t* las_ptr;

static __device__ __forceinline__ ushort_t f2bf(float x) {
  uint32_t u = __float_as_uint(x);
  u += 0x7fffu + ((u >> 16) & 1u);   // RNE
  return (ushort_t)(u >> 16);
}

// fp32 -> bf16 convert + per-64-row sum of squares -> aux transform.
// MODE 0 (Q): auxf[row] = 1e-6 * exp2(+C2*sumsq)
// MODE 1 (K): auxu[row] = pack_bf16x2(lb'), lb' = -0.5*sumsq + 8*ln(mask)
template <int MODE>
__global__ __launch_bounds__(256) void k_cvt(const float* __restrict__ src,
                                             ushort_t* __restrict__ dst,
                                             void* __restrict__ aux,
                                             const float* __restrict__ mask) {
  int t = blockIdx.x * 256 + threadIdx.x;
  int row = t >> 2, part = t & 3;
  const float4* p = reinterpret_cast<const float4*>(src + (size_t)row * 64 + part * 16);
  uint_t o[8];
  float s = 0.f;
#pragma unroll
  for (int i = 0; i < 4; ++i) {
    float4 v = p[i];
    s += v.x * v.x + v.y * v.y + v.z * v.z + v.w * v.w;
    o[2 * i]     = (uint_t)f2bf(v.x) | ((uint_t)f2bf(v.y) << 16);
    o[2 * i + 1] = (uint_t)f2bf(v.z) | ((uint_t)f2bf(v.w) << 16);
  }
  uint4* dp = reinterpret_cast<uint4*>(dst + (size_t)row * 64 + part * 16);
  dp[0] = make_uint4(o[0], o[1], o[2], o[3]);
  dp[1] = make_uint4(o[4], o[5], o[6], o[7]);
  s += __shfl_xor(s, 1);
  s += __shfl_xor(s, 2);
  if (part == 0) {
    if (MODE == 0) {
      ((float*)aux)[row] = 1e-6f * exp2f(C2 * s);
    } else {
      int n = row >> 14;          // / (H*S)
      int sidx = row & (S_ - 1);  // % S
      float m = mask[n * S_ + sidx];
      float lbq = -0.5f * s + 8.f * __logf(m);   // m=0 -> -inf -> p=0
      ushort_t hi = f2bf(lbq);
      float hif = __uint_as_float((uint32_t)hi << 16);
      float lo = lbq - hif;
      if (!(lbq > -1e30f)) lo = 0.f;             // avoid inf-inf = NaN
      ((uint_t*)aux)[row] = (uint_t)hi | ((uint_t)f2bf(lo) << 16);
    }
  }
}

// V [n][s][h][64] fp32 -> V^T bf16 [n][h][d][sigma(s)], 64x64 tile via LDS.
// sigma: stored position p holds source s = p with bits 2 and 3 swapped
// (so PV B-fragments match the QK C/D register order -> zero-shuffle P).
__global__ __launch_bounds__(256) void k_vt(const float* __restrict__ v,
                                            ushort_t* __restrict__ vt) {
  __shared__ __align__(16) ushort_t tile[64][68];
  const int n = blockIdx.z, h = blockIdx.y, sc = blockIdx.x;
  const int t = threadIdx.x;
  const int sl = t >> 4;
  const int dp = (t & 15) * 4;
#pragma unroll
  for (int i = 0; i < 4; ++i) {
    int s = sc * 64 + i * 16 + sl;
    float4 val = *reinterpret_cast<const float4*>(
        v + (((size_t)n * S_ + s) * H_ + h) * 64 + dp);
    tile[dp + 0][i * 16 + sl] = f2bf(val.x);
    tile[dp + 1][i * 16 + sl] = f2bf(val.y);
    tile[dp + 2][i * 16 + sl] = f2bf(val.z);
    tile[dp + 3][i * 16 + sl] = f2bf(val.w);
  }
  __syncthreads();
  const int d = t >> 2, sp = (t & 3) * 16;
  uint_t o[8];
#pragma unroll
  for (int i = 0; i < 8; ++i) {
    const int p0 = sp + 2 * i, p1 = p0 + 1;
    const int s0 = (p0 & ~12) | ((p0 & 4) << 1) | ((p0 & 8) >> 1);
    const int s1 = (p1 & ~12) | ((p1 & 4) << 1) | ((p1 & 8) >> 1);
    o[i] = (uint_t)tile[d][s0] | ((uint_t)tile[d][s1] << 16);
  }
  size_t base = ((size_t)(n * H_ + h) * 64 + d) * S_ + sc * 64 + sp;
  uint4* w = reinterpret_cast<uint4*>(vt + base);
  w[0] = make_uint4(o[0], o[1], o[2], o[3]);
  w[1] = make_uint4(o[4], o[5], o[6], o[7]);
}

// Main kernel: 4 waves/block, wave owns 32 q-rows, chunk = 64 keys,
// 32x32x16 MFMA, double-buffered K/V staging, one barrier per chunk.
__global__ __launch_bounds__(256, 2) void k_attn(
    const ushort_t* __restrict__ qb, const ushort_t* __restrict__ kbuf,
    const ushort_t* __restrict__ vt, const float* __restrict__ epsq,
    const uint_t* __restrict__ lbp, float* __restrict__ out) {
  __shared__ __align__(16) ushort_t kt[2][64 * 64];
  __shared__ __align__(16) ushort_t vtt[2][64 * 64];
  __shared__ float zb[4][32];

  const int lane = threadIdx.x & 63;
  const int w = threadIdx.x >> 6;
  const int c = lane & 31;    // q-col / d-col / key-row-in-32-block
  const int hl = lane >> 5;   // lane half -> k-slot half
  const int l7 = lane & 7;    // row&7 for swizzle
  const int qt = blockIdx.x, hd = blockIdx.y, n = blockIdx.z;
  const int nh = n * H_ + hd;
  const int qrow0 = qt * 128 + w * 32;

  // Q as B-operand: lane holds Q[qrow0+c][e = es*16 + hl*8 + b]
  const ushort_t* qbase = qb + ((size_t)nh * L_ + qrow0) * 64;
  b8 qf[4];
#pragma unroll
  for (int es = 0; es < 4; ++es)
    qf[es] = *reinterpret_cast<const b8*>(qbase + c * 64 + es * 16 + hl * 8);

  const ushort_t* kbh = kbuf + (size_t)nh * S_ * 64;
  const ushort_t* vth = vt + (size_t)nh * 64 * S_;
  const uint_t* lph = lbp + (size_t)nh * S_;

  f16v zero16 = {};
  f16v acc[2] = {zero16, zero16};
  float rs = 0.f;

  const int lrow = lane >> 3;          // staging row in 8-row piece
  const int lc16 = (lane & 7) ^ lrow;  // pre-swizzled global 16B slot

  // ones B-frag for the lb-MFMA (1.0bf16 at k-slots 0,1 only)
  union U4 { uint_t u[4]; b8 v; };
  U4 of; of.u[0] = hl == 0 ? 0x3f803f80u : 0u; of.u[1] = of.u[2] = of.u[3] = 0u;

#define STAGE(buf, ch)                                                         \
  {                                                                            \
    _Pragma("unroll")                                                          \
    for (int t2 = 0; t2 < 2; ++t2) {                                           \
      const int rr = w * 16 + t2 * 8;                                          \
      const ushort_t* gk = kbh + ((size_t)(ch) * 64 + rr + lrow) * 64 + lc16 * 8; \
      __builtin_amdgcn_global_load_lds((gas_ptr)gk, (las_ptr)(&kt[buf][rr * 64]), 16, 0, 0); \
      const ushort_t* gv = vth + (size_t)(rr + lrow) * S_ + (ch) * 64 + lc16 * 8; \
      __builtin_amdgcn_global_load_lds((gas_ptr)gv, (las_ptr)(&vtt[buf][rr * 64]), 16, 0, 0); \
    }                                                                          \
  }

  STAGE(0, 0);
  __syncthreads();

  for (int ch = 0; ch < 32; ++ch) {
    const int buf = ch & 1;
    if (ch < 31) STAGE(buf ^ 1, ch + 1);

    const uint_t lb0 = lph[ch * 64 + c];
    const uint_t lb1 = lph[ch * 64 + 32 + c];

    uint_t pw[16];
#pragma unroll
    for (int kbk = 0; kbk < 2; ++kbk) {
      U4 lf;
      lf.u[0] = hl == 0 ? (kbk ? lb1 : lb0) : 0u;
      lf.u[1] = lf.u[2] = lf.u[3] = 0u;
      f16v sa = __builtin_amdgcn_mfma_f32_32x32x16_bf16(lf.v, of.v, zero16, 0, 0, 0);
      const ushort_t* ktb = &kt[buf][0] + (32 * kbk + c) * 64;
      __builtin_amdgcn_s_setprio(1);
#pragma unroll
      for (int es = 0; es < 4; ++es) {
        b8 ak = *reinterpret_cast<const b8*>(ktb + ((2 * es + hl) ^ l7) * 8);
        sa = __builtin_amdgcn_mfma_f32_32x32x16_bf16(ak, qf[es], sa, 0, 0, 0);
      }
      __builtin_amdgcn_s_setprio(0);
      // p = exp2(C1 * sa); pack pairs (reg order == PV A-frag order)
#pragma unroll
      for (int i = 0; i < 8; ++i) {
        float p0 = exp2f(C1 * sa[2 * i]);
        float p1 = exp2f(C1 * sa[2 * i + 1]);
        rs += p0 + p1;
        asm("v_cvt_pk_bf16_f32 %0, %1, %2" : "=v"(pw[8 * kbk + i]) : "v"(p0), "v"(p1));
      }
    }

    // PV: acc[db] += P(32q x 16s) * V'(16s x 32d), 4 key-slices j
    __builtin_amdgcn_s_setprio(1);
#pragma unroll
    for (int j = 0; j < 4; ++j) {
      U4 pa;
      const int pb = 8 * (j >> 1) + 4 * (j & 1);
      pa.u[0] = pw[pb + 0]; pa.u[1] = pw[pb + 1];
      pa.u[2] = pw[pb + 2]; pa.u[3] = pw[pb + 3];
#pragma unroll
      for (int db = 0; db < 2; ++db) {
        b8 bv = *reinterpret_cast<const b8*>(
            &vtt[buf][0] + (32 * db + c) * 64 + ((2 * j + hl) ^ l7) * 8);
        acc[db] = __builtin_amdgcn_mfma_f32_32x32x16_bf16(pa.v, bv, acc[db], 0, 0, 0);
      }
    }
    __builtin_amdgcn_s_setprio(0);

    __syncthreads();
  }
#undef STAGE

  // Z per q-row: lane c and c+32 hold complementary key-halves
  rs += __shfl_xor(rs, 32);
  float z = 1.f / (rs + epsq[(size_t)nh * L_ + qrow0 + c]);
  if (hl == 0) zb[w][c] = z;
  __syncthreads();

  f4 zz[4];
#pragma unroll
  for (int r2 = 0; r2 < 4; ++r2)
    zz[r2] = *reinterpret_cast<const f4*>(&zb[w][8 * r2 + 4 * hl]);

  // out[n][qrow0 + R(reg,hl)][hd][32*db + c], R = (reg&3)+8*(reg>>2)+4*hl
  float* ob = out + (((size_t)n * L_ + qrow0) * H_ + hd) * 64;
#pragma unroll
  for (int db = 0; db < 2; ++db) {
#pragma unroll
    for (int reg = 0; reg < 16; ++reg) {
      const int R = (reg & 3) + 8 * (reg >> 2) + 4 * hl;
      ob[(size_t)R * (H_ * 64) + 32 * db + c] = acc[db][reg] * zz[reg >> 2][reg & 3];
    }
  }
}

extern "C" void kernel_launch(void* const* d_in, const int* in_sizes, int n_in,
                              void* d_out, int out_size, void* d_ws, size_t ws_size,
                              hipStream_t stream) {
  const float* q = (const float*)d_in[0];
  const float* k = (const float*)d_in[1];
  const float* v = (const float*)d_in[2];
  const float* mask = (const float*)d_in[3];
  float* out = (float*)d_out;

  char* ws = (char*)d_ws;
  ushort_t* qb = (ushort_t*)ws;
  ushort_t* kb = (ushort_t*)(ws + ((size_t)8 << 20));
  ushort_t* vt = (ushort_t*)(ws + ((size_t)16 << 20));
  float* epsq = (float*)(ws + ((size_t)24 << 20));
  uint_t* lbp = (uint_t*)(ws + ((size_t)24 << 20) + ((size_t)1 << 18));

  k_cvt<0><<<dim3(1024), dim3(256), 0, stream>>>(q, qb, (void*)epsq, nullptr);
  k_cvt<1><<<dim3(1024), dim3(256), 0, stream>>>(k, kb, (void*)lbp, mask);
  k_vt<<<dim3(S_ / 64, H_, N_), dim3(256), 0, stream>>>(v, vt);
  k_attn<<<dim3(L_ / 128, H_, N_), dim3(256), 0, stream>>>(qb, kb, vt, epsq,
                                                           lbp, out);
}